// Round 9
// baseline (121.433 us; speedup 1.0000x reference)
//
#include <hip/hip_runtime.h>
#include <math.h>

#define D 128
#define EPS 1e-7f

typedef unsigned int uint;
typedef float  f32x4  __attribute__((ext_vector_type(4)));   // native vecs for
typedef uint   u32x2  __attribute__((ext_vector_type(2)));   // nontemporal builtins
typedef uint   u32x4  __attribute__((ext_vector_type(4)));

__device__ __forceinline__ int sdot4(int a, int b, int c) {
#if __has_builtin(__builtin_amdgcn_sdot4)
    return __builtin_amdgcn_sdot4(a, b, c, false);   // v_dot4_i32_i8
#else
    int r = c;
    #pragma unroll
    for (int i = 0; i < 4; ++i) {
        int av = (a << (24 - 8 * i)) >> 24;
        int bv = (b << (24 - 8 * i)) >> 24;
        r += av * bv;
    }
    return r;
#endif
}

__device__ __forceinline__ uint pack4(f32x4 a, float inv) {
    const int q0 = (int)rintf(fminf(fmaxf(a.x * inv, -127.f), 127.f));
    const int q1 = (int)rintf(fminf(fmaxf(a.y * inv, -127.f), 127.f));
    const int q2 = (int)rintf(fminf(fmaxf(a.z * inv, -127.f), 127.f));
    const int q3 = (int)rintf(fminf(fmaxf(a.w * inv, -127.f), 127.f));
    return (uint)(q0 & 255) | ((uint)(q1 & 255) << 8)
         | ((uint)(q2 & 255) << 16) | ((uint)q3 << 24);
}

// ---------------- Kernel 1: per-node precompute ----------------
// m[n] = z[n]·W + b (exact f32, matches reference math).
// q[n] = round(z[n]/s_n) int8, s_n = rowmax/127; row = 32 dwords (128 B).
// meta[n] = {s_n, nrm_n = s_n^2·Σq², m_n, 0}.
// 16 lanes per node, 4 nodes per wave; z reads and zq/meta writes are
// non-temporal (read-once / write-once streams — keep L2 for the edge pass).
__global__ __launch_bounds__(256) void node_precompute_kernel(
    const float* __restrict__ z, const float* __restrict__ W,
    const float* __restrict__ b,
    uint* __restrict__ zq,        // [N, 32] dwords (128 i8 per row)
    float* __restrict__ meta, int N)   // [N, 4]
{
    const int lane = threadIdx.x & 63;
    const int sub = lane & 15;
    const int n = (blockIdx.x * (blockDim.x >> 6) + (threadIdx.x >> 6)) * 4
                  + (lane >> 4);
    if (n >= N) return;

    const f32x4* zr = (const f32x4*)(z + (size_t)n * D);
    const f32x4 a0 = __builtin_nontemporal_load(zr + sub);
    const f32x4 a1 = __builtin_nontemporal_load(zr + sub + 16);
    const f32x4 w0 = ((const f32x4*)W)[sub];
    const f32x4 w1 = ((const f32x4*)W)[sub + 16];

    float dot = a0.x * w0.x + a0.y * w0.y + a0.z * w0.z + a0.w * w0.w
              + a1.x * w1.x + a1.y * w1.y + a1.z * w1.z + a1.w * w1.w;
    float amax = fmaxf(
        fmaxf(fmaxf(fabsf(a0.x), fabsf(a0.y)), fmaxf(fabsf(a0.z), fabsf(a0.w))),
        fmaxf(fmaxf(fabsf(a1.x), fabsf(a1.y)), fmaxf(fabsf(a1.z), fabsf(a1.w))));
    #pragma unroll
    for (int off = 8; off > 0; off >>= 1) {
        dot  += __shfl_xor(dot, off);
        amax  = fmaxf(amax, __shfl_xor(amax, off));
    }

    const float s   = amax * (1.0f / 127.0f);
    const float inv = 127.0f / fmaxf(amax, 1e-30f);

    u32x2 pk;
    pk.x = pack4(a0, inv);
    pk.y = pack4(a1, inv);
    // layout: dwords {2sub, 2sub+1} = elems {4sub..4sub+3, 64+4sub..67+4sub}
    // (order-independent math; layout identical for every row)
    __builtin_nontemporal_store(pk, (u32x2*)(zq + (size_t)n * 32) + sub);

    int S = sdot4((int)pk.x, (int)pk.x, 0);
    S     = sdot4((int)pk.y, (int)pk.y, S);
    #pragma unroll
    for (int off = 8; off > 0; off >>= 1) S += __shfl_xor(S, off);

    if (sub == 0) {
        f32x4 mt;
        mt.x = s;
        mt.y = (s * s) * (float)S;   // nrm; edge-side wc uses identical expr
        mt.z = dot + b[0];
        mt.w = 0.f;
        __builtin_nontemporal_store(mt, (f32x4*)meta + n);
    }
}

// ---------------- Kernel 2: per-edge ----------------
// 4 lanes per edge, 16 edges per wave. Lane sub loads row dwords
// [4sub..4sub+3] and [16+4sub..] (16 B each). Cross-dot exact i32 via
// sdot4; 2-step butterfly. Index loads and output stores are
// non-temporal so the zq/meta gather keeps the L2 to itself.
// dist2 = nrm_i + nrm_j − 2·si·sj·dot  (==0 exactly when src==dst).
__global__ __launch_bounds__(256) void edge_kernel(
    const uint* __restrict__ zq, const float* __restrict__ meta,
    const int* __restrict__ ei, float* __restrict__ out, int E)
{
    const int lane = threadIdx.x & 63;
    const int sub = lane & 3;
    const int e = (blockIdx.x * (blockDim.x >> 6) + (threadIdx.x >> 6)) * 16
                  + (lane >> 2);
    if (e >= E) return;

    const int src = __builtin_nontemporal_load(ei + e);
    const int dst = __builtin_nontemporal_load(ei + E + e);

    const f32x4 Mi = ((const f32x4*)meta)[src];   // 1.6 MB table, L2-resident
    const f32x4 Mj = ((const f32x4*)meta)[dst];

    const u32x4* ri = (const u32x4*)(zq + (size_t)src * 32);
    const u32x4* rj = (const u32x4*)(zq + (size_t)dst * 32);
    const u32x4 a0 = ri[sub];
    const u32x4 a1 = ri[sub + 4];
    const u32x4 c0 = rj[sub];
    const u32x4 c1 = rj[sub + 4];

    int dot = sdot4((int)a0.x, (int)c0.x, 0);
    dot = sdot4((int)a0.y, (int)c0.y, dot);
    dot = sdot4((int)a0.z, (int)c0.z, dot);
    dot = sdot4((int)a0.w, (int)c0.w, dot);
    dot = sdot4((int)a1.x, (int)c1.x, dot);
    dot = sdot4((int)a1.y, (int)c1.y, dot);
    dot = sdot4((int)a1.z, (int)c1.z, dot);
    dot = sdot4((int)a1.w, (int)c1.w, dot);

    dot += __shfl_xor(dot, 1);
    dot += __shfl_xor(dot, 2);

    if (sub == 0) {
        const float wc = (Mi.x * Mj.x) * (float)dot;
        const float dist2 = fmaxf(Mi.y + Mj.y - wc - wc, 0.0f) + EPS;
        const float logits = Mj.z - __logf(dist2);
        const float prob   = 1.0f / (1.0f + __expf(-logits));
        __builtin_nontemporal_store(logits, out + e);
        __builtin_nontemporal_store(prob,   out + E + e);
        __builtin_nontemporal_store(Mj.z,   out + 2 * E + e);
        __builtin_nontemporal_store(dist2,  out + 3 * E + e);
    }
}

// ---------------- Fallback if ws too small ----------------
__global__ __launch_bounds__(256) void gravity_decoder_fallback(
    const float* __restrict__ z, const int* __restrict__ ei,
    const float* __restrict__ W, const float* __restrict__ b,
    float* __restrict__ out, int E)
{
    const int lane = threadIdx.x & 63;
    const int half = lane >> 5, sub = lane & 31;
    const int e = (blockIdx.x * (blockDim.x >> 6) + (threadIdx.x >> 6)) * 2 + half;
    if (e >= E) return;
    const int src = ei[e], dst = ei[E + e];
    const float4* z4 = (const float4*)z;
    const float4 a = z4[(size_t)src * (D / 4) + sub];
    const float4 c = z4[(size_t)dst * (D / 4) + sub];
    const float4 w = ((const float4*)W)[sub];
    float dot = c.x * w.x + c.y * w.y + c.z * w.z + c.w * w.w;
    const float dx = a.x - c.x, dy = a.y - c.y, dz = a.z - c.z, dw = a.w - c.w;
    float d2 = dx * dx + dy * dy + dz * dz + dw * dw;
    #pragma unroll
    for (int off = 16; off > 0; off >>= 1) {
        dot += __shfl_xor(dot, off);
        d2  += __shfl_xor(d2,  off);
    }
    if (sub == 0) {
        const float mj = dot + b[0];
        const float dist2 = d2 + EPS;
        const float logits = mj - __logf(dist2);
        const float prob = 1.0f / (1.0f + __expf(-logits));
        out[e] = logits; out[E + e] = prob;
        out[2 * E + e] = mj; out[3 * E + e] = dist2;
    }
}

extern "C" void kernel_launch(void* const* d_in, const int* in_sizes, int n_in,
                              void* d_out, int out_size, void* d_ws, size_t ws_size,
                              hipStream_t stream)
{
    const float* z  = (const float*)d_in[0];
    const int*   ei = (const int*)d_in[1];
    const float* W  = (const float*)d_in[2];
    const float* b  = (const float*)d_in[3];
    float* out = (float*)d_out;

    const int E = in_sizes[1] / 2;   // edge_index is [2, E]
    const int N = in_sizes[0] / D;   // z is [N, 128]

    const size_t zq_bytes   = (size_t)N * D;              // i8 rows, 128 B
    const size_t meta_bytes = (size_t)N * 4 * sizeof(float);

    if (ws_size >= zq_bytes + meta_bytes) {
        uint*  zq   = (uint*)d_ws;
        float* meta = (float*)((char*)d_ws + zq_bytes);

        const int nodes_per_block = 16;  // 4 nodes/wave x 4 waves
        node_precompute_kernel<<<(N + nodes_per_block - 1) / nodes_per_block,
                                 256, 0, stream>>>(z, W, b, zq, meta, N);

        const int edges_per_block = 64;  // 16 edges/wave x 4 waves
        edge_kernel<<<(E + edges_per_block - 1) / edges_per_block,
                      256, 0, stream>>>(zq, meta, ei, out, E);
    } else {
        const int edges_per_block = 8;
        gravity_decoder_fallback<<<(E + edges_per_block - 1) / edges_per_block,
                                   256, 0, stream>>>(z, ei, W, b, out, E);
    }
}

// Round 10
// 121.420 us; speedup vs baseline: 1.0001x; 1.0001x over previous
//
#include <hip/hip_runtime.h>
#include <math.h>

#define D 128
#define EPS 1e-7f

typedef unsigned int uint;
typedef float  f32x4  __attribute__((ext_vector_type(4)));   // native vecs for
typedef uint   u32x2  __attribute__((ext_vector_type(2)));   // nontemporal builtins
typedef uint   u32x4  __attribute__((ext_vector_type(4)));

__device__ __forceinline__ int sdot4(int a, int b, int c) {
#if __has_builtin(__builtin_amdgcn_sdot4)
    return __builtin_amdgcn_sdot4(a, b, c, false);   // v_dot4_i32_i8
#else
    int r = c;
    #pragma unroll
    for (int i = 0; i < 4; ++i) {
        int av = (a << (24 - 8 * i)) >> 24;
        int bv = (b << (24 - 8 * i)) >> 24;
        r += av * bv;
    }
    return r;
#endif
}

__device__ __forceinline__ uint pack4(f32x4 a, float inv) {
    const int q0 = (int)rintf(fminf(fmaxf(a.x * inv, -127.f), 127.f));
    const int q1 = (int)rintf(fminf(fmaxf(a.y * inv, -127.f), 127.f));
    const int q2 = (int)rintf(fminf(fmaxf(a.z * inv, -127.f), 127.f));
    const int q3 = (int)rintf(fminf(fmaxf(a.w * inv, -127.f), 127.f));
    return (uint)(q0 & 255) | ((uint)(q1 & 255) << 8)
         | ((uint)(q2 & 255) << 16) | ((uint)q3 << 24);
}

// ---------------- Kernel 1: per-node precompute ----------------
// m[n] = z[n]·W + b (exact f32, matches reference math).
// q[n] = round(z[n]/s_n) int8, s_n = rowmax/127; row = 32 dwords (128 B).
// meta[n] = {s_n, nrm_n = s_n^2·Σq², m_n, 0}.
// 16 lanes per node, 4 nodes per wave. z reads are non-temporal
// (read-once); zq/meta stores are NORMAL — they are re-read by the edge
// kernel and should stay in L2 (R9 post-mortem: nt stores here cost 3 µs).
__global__ __launch_bounds__(256) void node_precompute_kernel(
    const float* __restrict__ z, const float* __restrict__ W,
    const float* __restrict__ b,
    uint* __restrict__ zq,        // [N, 32] dwords (128 i8 per row)
    float* __restrict__ meta, int N)   // [N, 4]
{
    const int lane = threadIdx.x & 63;
    const int sub = lane & 15;
    const int n = (blockIdx.x * (blockDim.x >> 6) + (threadIdx.x >> 6)) * 4
                  + (lane >> 4);
    if (n >= N) return;

    const f32x4* zr = (const f32x4*)(z + (size_t)n * D);
    const f32x4 a0 = __builtin_nontemporal_load(zr + sub);
    const f32x4 a1 = __builtin_nontemporal_load(zr + sub + 16);
    const f32x4 w0 = ((const f32x4*)W)[sub];
    const f32x4 w1 = ((const f32x4*)W)[sub + 16];

    float dot = a0.x * w0.x + a0.y * w0.y + a0.z * w0.z + a0.w * w0.w
              + a1.x * w1.x + a1.y * w1.y + a1.z * w1.z + a1.w * w1.w;
    float amax = fmaxf(
        fmaxf(fmaxf(fabsf(a0.x), fabsf(a0.y)), fmaxf(fabsf(a0.z), fabsf(a0.w))),
        fmaxf(fmaxf(fabsf(a1.x), fabsf(a1.y)), fmaxf(fabsf(a1.z), fabsf(a1.w))));
    #pragma unroll
    for (int off = 8; off > 0; off >>= 1) {
        dot  += __shfl_xor(dot, off);
        amax  = fmaxf(amax, __shfl_xor(amax, off));
    }

    const float s   = amax * (1.0f / 127.0f);
    const float inv = 127.0f / fmaxf(amax, 1e-30f);

    u32x2 pk;
    pk.x = pack4(a0, inv);
    pk.y = pack4(a1, inv);
    // layout: dwords {2sub, 2sub+1} = elems {4sub..4sub+3, 64+4sub..67+4sub}
    // (order-independent math; layout identical for every row)
    ((u32x2*)(zq + (size_t)n * 32))[sub] = pk;   // normal store: L2-resident

    int S = sdot4((int)pk.x, (int)pk.x, 0);
    S     = sdot4((int)pk.y, (int)pk.y, S);
    #pragma unroll
    for (int off = 8; off > 0; off >>= 1) S += __shfl_xor(S, off);

    if (sub == 0) {
        f32x4 mt;
        mt.x = s;
        mt.y = (s * s) * (float)S;   // nrm; edge-side wc uses identical expr
        mt.z = dot + b[0];
        mt.w = 0.f;
        ((f32x4*)meta)[n] = mt;      // normal store: L2-resident
    }
}

// ---------------- Kernel 2: per-edge ----------------
// 4 lanes per edge, 16 edges per wave. Lane sub loads row dwords
// [4sub..4sub+3] and [16+4sub..] (16 B each). Cross-dot exact i32 via
// sdot4; 2-step butterfly. Index loads and output stores non-temporal
// (zero reuse) so the zq/meta gather keeps the L2 to itself.
// dist2 = nrm_i + nrm_j − 2·si·sj·dot  (==0 exactly when src==dst).
__global__ __launch_bounds__(256) void edge_kernel(
    const uint* __restrict__ zq, const float* __restrict__ meta,
    const int* __restrict__ ei, float* __restrict__ out, int E)
{
    const int lane = threadIdx.x & 63;
    const int sub = lane & 3;
    const int e = (blockIdx.x * (blockDim.x >> 6) + (threadIdx.x >> 6)) * 16
                  + (lane >> 2);
    if (e >= E) return;

    const int src = __builtin_nontemporal_load(ei + e);
    const int dst = __builtin_nontemporal_load(ei + E + e);

    const f32x4 Mi = ((const f32x4*)meta)[src];   // 1.6 MB table, L2-resident
    const f32x4 Mj = ((const f32x4*)meta)[dst];

    const u32x4* ri = (const u32x4*)(zq + (size_t)src * 32);
    const u32x4* rj = (const u32x4*)(zq + (size_t)dst * 32);
    const u32x4 a0 = ri[sub];
    const u32x4 a1 = ri[sub + 4];
    const u32x4 c0 = rj[sub];
    const u32x4 c1 = rj[sub + 4];

    int dot = sdot4((int)a0.x, (int)c0.x, 0);
    dot = sdot4((int)a0.y, (int)c0.y, dot);
    dot = sdot4((int)a0.z, (int)c0.z, dot);
    dot = sdot4((int)a0.w, (int)c0.w, dot);
    dot = sdot4((int)a1.x, (int)c1.x, dot);
    dot = sdot4((int)a1.y, (int)c1.y, dot);
    dot = sdot4((int)a1.z, (int)c1.z, dot);
    dot = sdot4((int)a1.w, (int)c1.w, dot);

    dot += __shfl_xor(dot, 1);
    dot += __shfl_xor(dot, 2);

    if (sub == 0) {
        const float wc = (Mi.x * Mj.x) * (float)dot;
        const float dist2 = fmaxf(Mi.y + Mj.y - wc - wc, 0.0f) + EPS;
        const float logits = Mj.z - __logf(dist2);
        const float prob   = 1.0f / (1.0f + __expf(-logits));
        __builtin_nontemporal_store(logits, out + e);
        __builtin_nontemporal_store(prob,   out + E + e);
        __builtin_nontemporal_store(Mj.z,   out + 2 * E + e);
        __builtin_nontemporal_store(dist2,  out + 3 * E + e);
    }
}

// ---------------- Fallback if ws too small ----------------
__global__ __launch_bounds__(256) void gravity_decoder_fallback(
    const float* __restrict__ z, const int* __restrict__ ei,
    const float* __restrict__ W, const float* __restrict__ b,
    float* __restrict__ out, int E)
{
    const int lane = threadIdx.x & 63;
    const int half = lane >> 5, sub = lane & 31;
    const int e = (blockIdx.x * (blockDim.x >> 6) + (threadIdx.x >> 6)) * 2 + half;
    if (e >= E) return;
    const int src = ei[e], dst = ei[E + e];
    const float4* z4 = (const float4*)z;
    const float4 a = z4[(size_t)src * (D / 4) + sub];
    const float4 c = z4[(size_t)dst * (D / 4) + sub];
    const float4 w = ((const float4*)W)[sub];
    float dot = c.x * w.x + c.y * w.y + c.z * w.z + c.w * w.w;
    const float dx = a.x - c.x, dy = a.y - c.y, dz = a.z - c.z, dw = a.w - c.w;
    float d2 = dx * dx + dy * dy + dz * dz + dw * dw;
    #pragma unroll
    for (int off = 16; off > 0; off >>= 1) {
        dot += __shfl_xor(dot, off);
        d2  += __shfl_xor(d2,  off);
    }
    if (sub == 0) {
        const float mj = dot + b[0];
        const float dist2 = d2 + EPS;
        const float logits = mj - __logf(dist2);
        const float prob = 1.0f / (1.0f + __expf(-logits));
        out[e] = logits; out[E + e] = prob;
        out[2 * E + e] = mj; out[3 * E + e] = dist2;
    }
}

extern "C" void kernel_launch(void* const* d_in, const int* in_sizes, int n_in,
                              void* d_out, int out_size, void* d_ws, size_t ws_size,
                              hipStream_t stream)
{
    const float* z  = (const float*)d_in[0];
    const int*   ei = (const int*)d_in[1];
    const float* W  = (const float*)d_in[2];
    const float* b  = (const float*)d_in[3];
    float* out = (float*)d_out;

    const int E = in_sizes[1] / 2;   // edge_index is [2, E]
    const int N = in_sizes[0] / D;   // z is [N, 128]

    const size_t zq_bytes   = (size_t)N * D;              // i8 rows, 128 B
    const size_t meta_bytes = (size_t)N * 4 * sizeof(float);

    if (ws_size >= zq_bytes + meta_bytes) {
        uint*  zq   = (uint*)d_ws;
        float* meta = (float*)((char*)d_ws + zq_bytes);

        const int nodes_per_block = 16;  // 4 nodes/wave x 4 waves
        node_precompute_kernel<<<(N + nodes_per_block - 1) / nodes_per_block,
                                 256, 0, stream>>>(z, W, b, zq, meta, N);

        const int edges_per_block = 64;  // 16 edges/wave x 4 waves
        edge_kernel<<<(E + edges_per_block - 1) / edges_per_block,
                      256, 0, stream>>>(zq, meta, ei, out, E);
    } else {
        const int edges_per_block = 8;
        gravity_decoder_fallback<<<(E + edges_per_block - 1) / edges_per_block,
                                   256, 0, stream>>>(z, ei, W, b, out, E);
    }
}

// Round 11
// 118.099 us; speedup vs baseline: 1.0282x; 1.0281x over previous
//
#include <hip/hip_runtime.h>
#include <math.h>

#define D 128
#define EPS 1e-7f

typedef unsigned int uint;

__device__ __forceinline__ int sdot4(int a, int b, int c) {
#if __has_builtin(__builtin_amdgcn_sdot4)
    return __builtin_amdgcn_sdot4(a, b, c, false);   // v_dot4_i32_i8
#else
    int r = c;
    #pragma unroll
    for (int i = 0; i < 4; ++i) {
        int av = (a << (24 - 8 * i)) >> 24;
        int bv = (b << (24 - 8 * i)) >> 24;
        r += av * bv;
    }
    return r;
#endif
}

// ---------------- Kernel 1: per-node precompute ----------------
// m[n] = z[n]·W + b (exact f32, matches reference math).
// q[n] = round(z[n]/s_n) int8, s_n = rowmax/127; row = 32 dwords (128 B).
// meta[n] = {s_n, nrm_n = s_n^2·Σq², m_n, 0} as float4.
// 32 lanes per node, 2 nodes per wave.
// NOTE (R8-R10 post-mortem): nt-hint variants and 16-lane restructure all
// measured neutral-to-worse (121.4 vs this config's 118.3) — keep plain.
__global__ __launch_bounds__(256) void node_precompute_kernel(
    const float* __restrict__ z, const float* __restrict__ W,
    const float* __restrict__ b,
    uint* __restrict__ zq,        // [N, 32] dwords (128 i8 per row)
    float4* __restrict__ meta, int N)
{
    const int lane = threadIdx.x & 63;
    const int half = lane >> 5, sub = lane & 31;
    const int n = (blockIdx.x * (blockDim.x >> 6) + (threadIdx.x >> 6)) * 2 + half;
    if (n >= N) return;

    const float4 a = ((const float4*)(z + (size_t)n * D))[sub];
    const float4 w = ((const float4*)W)[sub];

    float dot = a.x * w.x + a.y * w.y + a.z * w.z + a.w * w.w;
    float amax = fmaxf(fmaxf(fabsf(a.x), fabsf(a.y)), fmaxf(fabsf(a.z), fabsf(a.w)));
    #pragma unroll
    for (int off = 16; off > 0; off >>= 1) {
        dot  += __shfl_xor(dot, off);
        amax  = fmaxf(amax, __shfl_xor(amax, off));
    }

    const float s   = amax * (1.0f / 127.0f);
    const float inv = 127.0f / fmaxf(amax, 1e-30f);

    const int q0 = (int)rintf(fminf(fmaxf(a.x * inv, -127.f), 127.f));
    const int q1 = (int)rintf(fminf(fmaxf(a.y * inv, -127.f), 127.f));
    const int q2 = (int)rintf(fminf(fmaxf(a.z * inv, -127.f), 127.f));
    const int q3 = (int)rintf(fminf(fmaxf(a.w * inv, -127.f), 127.f));
    const uint pack = (uint)(q0 & 255) | ((uint)(q1 & 255) << 8)
                    | ((uint)(q2 & 255) << 16) | ((uint)q3 << 24);
    zq[(size_t)n * 32 + sub] = pack;

    int S = sdot4((int)pack, (int)pack, 0);
    #pragma unroll
    for (int off = 16; off > 0; off >>= 1) S += __shfl_xor(S, off);

    if (sub == 0) {
        float4 mt;
        mt.x = s;
        mt.y = (s * s) * (float)S;   // nrm; edge-side wc uses identical expr
        mt.z = dot + b[0];
        mt.w = 0.f;
        meta[n] = mt;
    }
}

// ---------------- Kernel 2: per-edge ----------------
// 4 lanes per edge, 16 edges per wave. Lane sub loads row[sub] and
// row[sub+4] (uint4 each) -> each load instr covers one 64 B half-row
// per 4-lane group. Cross-dot exact i32 via sdot4; 2-step butterfly.
// dist2 = nrm_i + nrm_j − 2·si·sj·dot  (==0 exactly when src==dst).
__global__ __launch_bounds__(256) void edge_kernel(
    const uint* __restrict__ zq, const float4* __restrict__ meta,
    const int* __restrict__ ei, float* __restrict__ out, int E)
{
    const int lane = threadIdx.x & 63;
    const int sub = lane & 3;
    const int e = (blockIdx.x * (blockDim.x >> 6) + (threadIdx.x >> 6)) * 16
                  + (lane >> 2);
    if (e >= E) return;

    const int src = ei[e];
    const int dst = ei[E + e];

    const float4 Mi = meta[src];     // 1.6 MB table, mostly L2-resident
    const float4 Mj = meta[dst];

    const uint4* ri = (const uint4*)(zq + (size_t)src * 32);
    const uint4* rj = (const uint4*)(zq + (size_t)dst * 32);
    const uint4 a0 = ri[sub];
    const uint4 a1 = ri[sub + 4];
    const uint4 c0 = rj[sub];
    const uint4 c1 = rj[sub + 4];

    int dot = sdot4((int)a0.x, (int)c0.x, 0);
    dot = sdot4((int)a0.y, (int)c0.y, dot);
    dot = sdot4((int)a0.z, (int)c0.z, dot);
    dot = sdot4((int)a0.w, (int)c0.w, dot);
    dot = sdot4((int)a1.x, (int)c1.x, dot);
    dot = sdot4((int)a1.y, (int)c1.y, dot);
    dot = sdot4((int)a1.z, (int)c1.z, dot);
    dot = sdot4((int)a1.w, (int)c1.w, dot);

    dot += __shfl_xor(dot, 1);
    dot += __shfl_xor(dot, 2);

    if (sub == 0) {
        const float wc = (Mi.x * Mj.x) * (float)dot;
        const float dist2 = fmaxf(Mi.y + Mj.y - wc - wc, 0.0f) + EPS;
        const float logits = Mj.z - __logf(dist2);
        const float prob   = 1.0f / (1.0f + __expf(-logits));
        out[e]         = logits;   // 16 edges/wave -> 64 B contiguous/array
        out[E + e]     = prob;
        out[2 * E + e] = Mj.z;
        out[3 * E + e] = dist2;
    }
}

// ---------------- Fallback if ws too small ----------------
__global__ __launch_bounds__(256) void gravity_decoder_fallback(
    const float* __restrict__ z, const int* __restrict__ ei,
    const float* __restrict__ W, const float* __restrict__ b,
    float* __restrict__ out, int E)
{
    const int lane = threadIdx.x & 63;
    const int half = lane >> 5, sub = lane & 31;
    const int e = (blockIdx.x * (blockDim.x >> 6) + (threadIdx.x >> 6)) * 2 + half;
    if (e >= E) return;
    const int src = ei[e], dst = ei[E + e];
    const float4* z4 = (const float4*)z;
    const float4 a = z4[(size_t)src * (D / 4) + sub];
    const float4 c = z4[(size_t)dst * (D / 4) + sub];
    const float4 w = ((const float4*)W)[sub];
    float dot = c.x * w.x + c.y * w.y + c.z * w.z + c.w * w.w;
    const float dx = a.x - c.x, dy = a.y - c.y, dz = a.z - c.z, dw = a.w - c.w;
    float d2 = dx * dx + dy * dy + dz * dz + dw * dw;
    #pragma unroll
    for (int off = 16; off > 0; off >>= 1) {
        dot += __shfl_xor(dot, off);
        d2  += __shfl_xor(d2,  off);
    }
    if (sub == 0) {
        const float mj = dot + b[0];
        const float dist2 = d2 + EPS;
        const float logits = mj - __logf(dist2);
        const float prob = 1.0f / (1.0f + __expf(-logits));
        out[e] = logits; out[E + e] = prob;
        out[2 * E + e] = mj; out[3 * E + e] = dist2;
    }
}

extern "C" void kernel_launch(void* const* d_in, const int* in_sizes, int n_in,
                              void* d_out, int out_size, void* d_ws, size_t ws_size,
                              hipStream_t stream)
{
    const float* z  = (const float*)d_in[0];
    const int*   ei = (const int*)d_in[1];
    const float* W  = (const float*)d_in[2];
    const float* b  = (const float*)d_in[3];
    float* out = (float*)d_out;

    const int E = in_sizes[1] / 2;   // edge_index is [2, E]
    const int N = in_sizes[0] / D;   // z is [N, 128]

    const size_t zq_bytes   = (size_t)N * D;              // i8 rows, 128 B
    const size_t meta_bytes = (size_t)N * sizeof(float4);

    if (ws_size >= zq_bytes + meta_bytes) {
        uint*   zq   = (uint*)d_ws;
        float4* meta = (float4*)((char*)d_ws + zq_bytes);

        const int nodes_per_block = 8;   // 2 nodes/wave x 4 waves
        node_precompute_kernel<<<(N + nodes_per_block - 1) / nodes_per_block,
                                 256, 0, stream>>>(z, W, b, zq, meta, N);

        const int edges_per_block = 64;  // 16 edges/wave x 4 waves
        edge_kernel<<<(E + edges_per_block - 1) / edges_per_block,
                      256, 0, stream>>>(zq, meta, ei, out, E);
    } else {
        const int edges_per_block = 8;
        gravity_decoder_fallback<<<(E + edges_per_block - 1) / edges_per_block,
                                   256, 0, stream>>>(z, ei, W, b, out, E);
    }
}